// Round 1
// 589.606 us; speedup vs baseline: 1.0900x; 1.0900x over previous
//
#include <hip/hip_runtime.h>
#include <math.h>

#define PI2 6.28318530717958647692f

// Problem constants: B=32, CI=CO=64, H=W=128, M1=M2=32.
// Interleaved complex intermediates (float2 = {re, im}):
//   Y  [bi=2048][h=128][ky=32]   (buf1)
//   Xf [bi=2048][kxi=64][ky=32]  (buf2)
//   T  [bo=2048][kxi=64][ky=32]  (buf1)
//   Z  [bo=2048][kxi=64][w'=65]  (buf2)
// out [b=32][o=64][h=128][w'=65] fp32

typedef short bf16x8 __attribute__((ext_vector_type(8)));
typedef float f32x4 __attribute__((ext_vector_type(4)));

static __device__ __forceinline__ ushort f2bf(float f) {
    uint u = __float_as_uint(f);
    u += 0x7FFFu + ((u >> 16) & 1u);  // round-to-nearest-even
    return (ushort)(u >> 16);
}
static __device__ __forceinline__ float bf2f(ushort h) {
    return __uint_as_float(((uint)h) << 16);
}

// ---------------- Twiddle init: E[w][col] for F1, stored as pre-swizzled ----
// LDS byte image. col = ky (cos) for col<32, col-32 = ky (-sin) for col>=32.
// Layout (ushort index): hi image [0,8192): col*128 + (w ^ ((col&7)<<3));
//                        lo image [8192,16384).
__global__ void k_einit(ushort* __restrict__ eimg) {
    int id = blockIdx.x * 256 + threadIdx.x;  // 0..8191
    int w = id & 127, col = id >> 7;
    int ky = col & 31, c = col >> 5;
    int m = (ky * w) & 127;
    float sv, cv;
    sincosf((float)m * (PI2 / 128.0f), &sv, &cv);
    float val = c ? -sv : cv;
    ushort hi = f2bf(val);
    float lo = val - bf2f(hi);
    int ui = col * 128 + (w ^ ((col & 7) << 3));
    eimg[ui] = hi;
    eimg[8192 + ui] = f2bf(lo);
}

// ---------------- Stage F1 (MFMA): x -> Y (row DFT over W, 32 modes) --------
// GEMM view: Y[rows][64cols] = x[rows][128] * E[128][64], rows = (bi,h).
// Split-bf16: x = xh + xl, E = eh + el; acc += xh*eh + xh*el + xl*eh.
// Block: 64 rows of one bi. 4 waves, each owns a 16-row tile x all 64 cols.
// LDS 64 KiB: E hi/lo (32 KiB, memcpy'd from eimg) + x hi/lo (32 KiB).
__global__ __launch_bounds__(256) void k_f1(const float* __restrict__ x,
                                            const ushort* __restrict__ eimg,
                                            float2* __restrict__ y) {
    __shared__ ushort lds[32768];  // 64 KiB
    const int bi = blockIdx.x;
    const int hbase = blockIdx.y * 64;
    const int t = threadIdx.x;

    // E hi+lo: straight 32 KiB copy (image is pre-swizzled).
    {
        const uint4* esrc = (const uint4*)eimg;
        uint4* edst = (uint4*)lds;
        for (int i = t; i < 2048; i += 256) edst[i] = esrc[i];
    }

    // x tile: load fp32, split into bf16 hi/lo, swizzled LDS write.
    const float* xp = x + (size_t)bi * 16384 + (size_t)hbase * 128;
    for (int i = 0; i < 4; i++) {
        int idx = i * 2048 + t * 8;          // element in [64 rows][128 w]
        int row = idx >> 7, w0 = idx & 127;
        float4 v0 = *(const float4*)&xp[idx];
        float4 v1 = *(const float4*)&xp[idx + 4];
        float vv[8] = {v0.x, v0.y, v0.z, v0.w, v1.x, v1.y, v1.z, v1.w};
        ushort h[8], l[8];
#pragma unroll
        for (int j = 0; j < 8; j++) {
            h[j] = f2bf(vv[j]);
            l[j] = f2bf(vv[j] - bf2f(h[j]));
        }
        uint4 hp, lp;
        hp.x = (uint)h[0] | ((uint)h[1] << 16);
        hp.y = (uint)h[2] | ((uint)h[3] << 16);
        hp.z = (uint)h[4] | ((uint)h[5] << 16);
        hp.w = (uint)h[6] | ((uint)h[7] << 16);
        lp.x = (uint)l[0] | ((uint)l[1] << 16);
        lp.y = (uint)l[2] | ((uint)l[3] << 16);
        lp.z = (uint)l[4] | ((uint)l[5] << 16);
        lp.w = (uint)l[6] | ((uint)l[7] << 16);
        int ui = row * 128 + (w0 ^ ((row & 7) << 3));
        *(uint4*)&lds[16384 + ui] = hp;
        *(uint4*)&lds[24576 + ui] = lp;
    }
    __syncthreads();

    const int lane = t & 63, wid = t >> 6;  // wid = row-tile
    const int ln = lane & 15, kq = lane >> 4;
    f32x4 acc[4] = {};
#pragma unroll
    for (int kk = 0; kk < 4; kk++) {
        int k0 = kk * 32 + kq * 8;
        int arow = wid * 16 + ln;
        int aui = arow * 128 + (k0 ^ ((arow & 7) << 3));
        bf16x8 ah = *(bf16x8*)&lds[16384 + aui];
        bf16x8 al = *(bf16x8*)&lds[24576 + aui];
#pragma unroll
        for (int nt = 0; nt < 4; nt++) {
            int col = nt * 16 + ln;
            int bui = col * 128 + (k0 ^ ((col & 7) << 3));
            bf16x8 bh = *(bf16x8*)&lds[bui];
            bf16x8 bl = *(bf16x8*)&lds[8192 + bui];
            acc[nt] = __builtin_amdgcn_mfma_f32_16x16x32_bf16(ah, bh, acc[nt], 0, 0, 0);
            acc[nt] = __builtin_amdgcn_mfma_f32_16x16x32_bf16(ah, bl, acc[nt], 0, 0, 0);
            acc[nt] = __builtin_amdgcn_mfma_f32_16x16x32_bf16(al, bh, acc[nt], 0, 0, 0);
        }
    }

    // C store: row=(lane>>4)*4+r, col=lane&15 within each 16x16 tile.
    // col<32 -> re of ky=col; col>=32 -> im of ky=col-32.
    float* yf = (float*)(y + (size_t)bi * 4096 + (size_t)hbase * 32);
    int rrow = wid * 16 + kq * 4;
#pragma unroll
    for (int nt = 0; nt < 4; nt++) {
        int col = nt * 16 + ln;
        int ky = col & 31, c = col >> 5;
#pragma unroll
        for (int r = 0; r < 4; r++)
            yf[((rrow + r) * 32 + ky) * 2 + c] = acc[nt][r];
    }
}

// ---------------- Stage F2: Y -> Xf (col DFT over H, 64 modes) ----------------
// Block: one bi image. 256 threads: 8 kyg x 32 kxg; thread = 2 kxi x 4 ky.
__global__ __launch_bounds__(256) void k_f2(const float2* __restrict__ y,
                                            float2* __restrict__ xf) {
    __shared__ float2 ys[4096];  // [h][ky], 32 KiB
    const int bi = blockIdx.x;
    const int t = threadIdx.x;
    const float2* yp = y + (size_t)bi * 4096;
    for (int idx = t; idx < 4096; idx += 256) ys[idx] = yp[idx];
    __syncthreads();
    const int kyg = t & 7, kxg = t >> 3;  // kxg 0..31
    const int ky0 = kyg * 4, kxi0 = kxg * 2;
    float c[2], s[2], dc[2], ds[2];
    float xr[2][4], xim[2][4];
    for (int jx = 0; jx < 2; jx++) {
        int kxi = kxi0 + jx;
        int kx = (kxi < 32) ? kxi : (kxi + 64);
        float th = -PI2 * (float)kx / 128.0f;
        sincosf(th, &ds[jx], &dc[jx]);
        c[jx] = 1.0f; s[jx] = 0.0f;
        for (int jy = 0; jy < 4; jy++) { xr[jx][jy] = 0.0f; xim[jx][jy] = 0.0f; }
    }
#pragma unroll 2
    for (int h = 0; h < 128; h++) {
        float2 yv[4];
        const float2* pp = &ys[h * 32 + ky0];
#pragma unroll
        for (int jy = 0; jy < 4; jy++) yv[jy] = pp[jy];
#pragma unroll
        for (int jx = 0; jx < 2; jx++) {
            float cc = c[jx], ss = s[jx];
#pragma unroll
            for (int jy = 0; jy < 4; jy++) {
                xr[jx][jy]  += cc * yv[jy].x - ss * yv[jy].y;
                xim[jx][jy] += cc * yv[jy].y + ss * yv[jy].x;
            }
            c[jx] = cc * dc[jx] - ss * ds[jx];
            s[jx] = ss * dc[jx] + cc * ds[jx];
        }
    }
    float2* xp = xf + (size_t)bi * 2048;
    for (int jx = 0; jx < 2; jx++) {
        int kxi = kxi0 + jx;
#pragma unroll
        for (int jy = 0; jy < 4; jy++)
            xp[kxi * 32 + ky0 + jy] = make_float2(xr[jx][jy], xim[jx][jy]);
    }
}

// ---------------- Stage M: channel mix, T = Xf @ conj(W) ----------------
__global__ __launch_bounds__(512) void k_mix(const float2* __restrict__ xf,
                                             const float* __restrict__ w1r, const float* __restrict__ w1i,
                                             const float* __restrict__ w2r, const float* __restrict__ w2i,
                                             float2* __restrict__ tt) {
    __shared__ float2 xfs[8192];  // [8 b][32 i][32 ky] per stage, 64 KiB
    const int kxi = blockIdx.x;       // 0..63
    const int b0 = blockIdx.y * 8;    // 4 groups of 8 b
    const int t = threadIdx.x;
    const int ky = t & 31, grp = t >> 5;  // grp 0..15
    const int o0 = grp * 4;
    const float* wr = (kxi < 32) ? w1r : w2r;
    const float* wi = (kxi < 32) ? w1i : w2i;
    const int kxim = kxi & 31;
    float accr[8][4], acci[8][4];
    for (int jb = 0; jb < 8; jb++)
        for (int jo = 0; jo < 4; jo++) { accr[jb][jo] = 0.0f; acci[jb][jo] = 0.0f; }

    for (int stage = 0; stage < 2; stage++) {
        const int ibase = stage * 32;
        __syncthreads();
        for (int idx = t; idx < 8192; idx += 512) {
            int b = idx >> 10, ii = (idx >> 5) & 31, kk = idx & 31;
            size_t g = ((size_t)(b0 + b) * 64 + (ibase + ii)) * 2048 + (size_t)kxi * 32 + kk;
            xfs[idx] = xf[g];
        }
        __syncthreads();
        for (int ii = 0; ii < 32; ii++) {
            const int i = ibase + ii;
            float wr4[4], wi4[4];
#pragma unroll
            for (int jo = 0; jo < 4; jo++) {
                size_t g = ((size_t)i * 64 + (o0 + jo)) * 1024 + (size_t)kxim * 32 + ky;
                wr4[jo] = wr[g]; wi4[jo] = wi[g];
            }
#pragma unroll
            for (int jb = 0; jb < 8; jb++) {
                float2 xv = xfs[(jb << 10) + (ii << 5) + ky];
#pragma unroll
                for (int jo = 0; jo < 4; jo++) {
                    accr[jb][jo] += xv.x * wr4[jo] + xv.y * wi4[jo];
                    acci[jb][jo] += xv.y * wr4[jo] - xv.x * wi4[jo];
                }
            }
        }
    }
    for (int jb = 0; jb < 8; jb++)
        for (int jo = 0; jo < 4; jo++) {
            size_t g = ((size_t)(b0 + jb) * 64 + (o0 + jo)) * 2048 + (size_t)kxi * 32 + ky;
            tt[g] = make_float2(accr[jb][jo], acci[jb][jo]);
        }
}

// ---------------- Stage I1: T -> Z (inverse DFT over ky -> 65 cols) ----------------
__global__ __launch_bounds__(256) void k_i1(const float2* __restrict__ tt,
                                            float2* __restrict__ z) {
    __shared__ float2 ts[2048];  // [kxi][ky], 16 KiB
    const int bo = blockIdx.x, t = threadIdx.x;
    const float2* tp = tt + (size_t)bo * 2048;
    for (int idx = t; idx < 2048; idx += 256) ts[idx] = tp[idx];
    __syncthreads();
    float2* zp = z + (size_t)bo * 4160;
    for (int p = t; p < 2080; p += 256) {
        int w = p % 65, kxi = p / 65;  // kxi 0..31, paired with kxi+32
        float dc, ds;
        sincosf(PI2 * (float)w / 65.0f, &ds, &dc);
        float c = 1.0f, s = 0.0f;
        float z1r = 0, z1i = 0, z2r = 0, z2i = 0;
        for (int ky = 0; ky < 32; ky++) {
            float2 t1 = ts[kxi * 32 + ky];
            float2 t2 = ts[(kxi + 32) * 32 + ky];
            z1r += t1.x * c - t1.y * s;
            z1i += t1.x * s + t1.y * c;
            z2r += t2.x * c - t2.y * s;
            z2i += t2.x * s + t2.y * c;
            float nc = c * dc - s * ds;
            s = s * dc + c * ds;
            c = nc;
        }
        zp[kxi * 65 + w] = make_float2(z1r, z1i);
        zp[(kxi + 32) * 65 + w] = make_float2(z2r, z2i);
    }
}

// ---------------- Stage I2: Z -> out (inverse DFT over H, real part) ----------------
// Row pairing: slot kxi (row kxi) and slot kxi+32 (row kxi+96).
// e^{2pi i * 96 h/128} = (-i)^h, so A(h) = Z1 + (-i)^h * Z2, out = Re(e^{2pi i kxi h/128} * A).
__global__ __launch_bounds__(256) void k_i2(const float2* __restrict__ z,
                                            float* __restrict__ out) {
    __shared__ float2 zs[64 * 68];  // [kxi][w'], padded to 68 (zero pad cols 65..67)
    const int bo = blockIdx.x, t = threadIdx.x;
    const float2* zp = z + (size_t)bo * 4160;
    for (int idx = t; idx < 64 * 68; idx += 256) {
        int kxi = idx / 68, w = idx % 68;
        float2 v = make_float2(0.0f, 0.0f);
        if (w < 65) v = zp[kxi * 65 + w];
        zs[idx] = v;
    }
    __syncthreads();
    float* op = out + (size_t)bo * 8320;
    const float scale = 1.0f / 8320.0f;  // 1/(128*65)
    for (int tile = t; tile < 544; tile += 256) {  // 32 hg * 17 wg
        int hg = tile / 17, wg = tile % 17;
        int h0 = hg * 4, w0 = wg * 4;
        float c[4], s[4], dc[4], ds[4], acc[4][4];
        for (int j = 0; j < 4; j++) {
            sincosf(PI2 * (float)(h0 + j) / 128.0f, &ds[j], &dc[j]);
            c[j] = 1.0f; s[j] = 0.0f;
            for (int k = 0; k < 4; k++) acc[j][k] = 0.0f;
        }
        for (int kxi = 0; kxi < 32; kxi++) {
            float2 z1[4], z2[4];
            const float2* p1 = &zs[kxi * 68 + w0];
            const float2* p2 = &zs[(kxi + 32) * 68 + w0];
#pragma unroll
            for (int k = 0; k < 4; k++) { z1[k] = p1[k]; z2[k] = p2[k]; }
#pragma unroll
            for (int k = 0; k < 4; k++) {
                float a0r = z1[k].x + z2[k].x, a0i = z1[k].y + z2[k].y;   // h%4==0: +Z2
                float a1r = z1[k].x + z2[k].y, a1i = z1[k].y - z2[k].x;   // h%4==1: -i*Z2
                float a2r = z1[k].x - z2[k].x, a2i = z1[k].y - z2[k].y;   // h%4==2: -Z2
                float a3r = z1[k].x - z2[k].y, a3i = z1[k].y + z2[k].x;   // h%4==3: +i*Z2
                acc[0][k] += c[0] * a0r - s[0] * a0i;
                acc[1][k] += c[1] * a1r - s[1] * a1i;
                acc[2][k] += c[2] * a2r - s[2] * a2i;
                acc[3][k] += c[3] * a3r - s[3] * a3i;
            }
#pragma unroll
            for (int j = 0; j < 4; j++) {
                float nc = c[j] * dc[j] - s[j] * ds[j];
                s[j] = s[j] * dc[j] + c[j] * ds[j];
                c[j] = nc;
            }
        }
        for (int j = 0; j < 4; j++)
            for (int k = 0; k < 4; k++) {
                int w = w0 + k;
                if (w < 65) op[(h0 + j) * 65 + w] = acc[j][k] * scale;
            }
    }
}

extern "C" void kernel_launch(void* const* d_in, const int* in_sizes, int n_in,
                              void* d_out, int out_size, void* d_ws, size_t ws_size,
                              hipStream_t stream) {
    const float* x   = (const float*)d_in[0];
    const float* w1r = (const float*)d_in[1];
    const float* w1i = (const float*)d_in[2];
    const float* w2r = (const float*)d_in[3];
    const float* w2i = (const float*)d_in[4];
    float2* ws = (float2*)d_ws;

    // buf1: Y (F1->F2) then T (mix->I1). Size max(8388608, 4194304) float2.
    // buf2: Xf (F2->mix) then Z (I1->I2). Size max(4194304, 8519680) float2.
    // E twiddle image (32 KiB) lives at the START of buf2 during F1 only;
    // F2's Xf write overwrites it after k_f1 has consumed it.
    float2* ya  = ws;
    float2* ta  = ws;
    float2* xfa = ws + 8388608;
    float2* za  = ws + 8388608;
    ushort* eimg = (ushort*)(ws + 8388608);
    float* out = (float*)d_out;

    k_einit<<<32, 256, 0, stream>>>(eimg);
    k_f1<<<dim3(2048, 2), 256, 0, stream>>>(x, eimg, ya);
    k_f2<<<2048, 256, 0, stream>>>(ya, xfa);
    k_mix<<<dim3(64, 4), 512, 0, stream>>>(xfa, w1r, w1i, w2r, w2i, ta);
    k_i1<<<2048, 256, 0, stream>>>(ta, za);
    k_i2<<<2048, 256, 0, stream>>>(za, out);
}

// Round 3
// 523.993 us; speedup vs baseline: 1.2265x; 1.1252x over previous
//
#include <hip/hip_runtime.h>
#include <math.h>

#define PI2 6.28318530717958647692f

// Problem constants: B=32, CI=CO=64, H=W=128, M1=M2=32.
// Intermediates:
//   Yimg [bi=2048][p=4][ky=32][h=128] ushort (bf16 planes: rh,rl,ih,il; swizzled)  (buf1, 64 MB)
//   Xf   [bi=2048][kxi=64][ky=32] float2   (buf2)
//   T    [bo=2048][kxi=64][ky=32] float2   (buf1)
//   Z    [bo=2048][kxi=64][w'=65] float2   (buf2)
// out [b=32][o=64][h=128][w'=65] fp32
// Swizzle (all bf16 images, granule = 8 ushorts): us_idx = row*128 + (k ^ ((row&7)<<3))

typedef short bf16x8 __attribute__((ext_vector_type(8)));
typedef float f32x4 __attribute__((ext_vector_type(4)));

static __device__ __forceinline__ ushort f2bf(float f) {
    uint u = __float_as_uint(f);
    u += 0x7FFFu + ((u >> 16) & 1u);  // round-to-nearest-even
    return (ushort)(u >> 16);
}
static __device__ __forceinline__ float bf2f(ushort h) {
    return __uint_as_float(((uint)h) << 16);
}

// ---------------- Twiddle init: E1 (F1) + E2 (F2) pre-swizzled images --------
// E1 (ushort idx): hi [0,8192): col*128 + (w ^ ((col&7)<<3)); lo [8192,16384).
//   col<32: cos(2pi ky w/128); col>=32: -sin(...).
// E2: 4 planes x [kxi=64][h=128]: p0=Er-hi p1=Er-lo p2=Ei-hi p3=Ei-lo,
//   Er=cos(2pi kx h/128), Ei=-sin(...), kx = kxi<32 ? kxi : kxi+64.
__global__ void k_einit(ushort* __restrict__ e1, ushort* __restrict__ e2) {
    int id = blockIdx.x * 256 + threadIdx.x;  // 0..16383
    if (id < 8192) {
        int w = id & 127, col = id >> 7;
        int ky = col & 31, csel = col >> 5;
        int m = (ky * w) & 127;
        float sv, cv;
        sincosf((float)m * (PI2 / 128.0f), &sv, &cv);
        float val = csel ? -sv : cv;
        ushort hi = f2bf(val);
        float lov = val - bf2f(hi);
        int ui = col * 128 + (w ^ ((col & 7) << 3));
        e1[ui] = hi;
        e1[8192 + ui] = f2bf(lov);
    } else {
        int id2 = id - 8192;
        int h = id2 & 127, kxi = id2 >> 7;
        int kx = (kxi < 32) ? kxi : (kxi + 64);
        int m = (kx * h) & 127;
        float sv, cv;
        sincosf((float)m * (PI2 / 128.0f), &sv, &cv);
        float er = cv, ei = -sv;
        int ui = kxi * 128 + (h ^ ((kxi & 7) << 3));
        ushort eh = f2bf(er);
        e2[ui] = eh;
        e2[8192 + ui] = f2bf(er - bf2f(eh));
        ushort ih = f2bf(ei);
        e2[16384 + ui] = ih;
        e2[24576 + ui] = f2bf(ei - bf2f(ih));
    }
}

// ---------------- Stage F1 (MFMA): x -> Yimg (row DFT over W, 32 modes) ------
// GEMM view: Y[rows][64cols] = x[rows][128] * E1[128][64], rows = (bi,h).
// Epilogue stores split-bf16 transposed planes [p][ky][h] (swizzled) for F2.
__global__ __launch_bounds__(256) void k_f1(const float* __restrict__ x,
                                            const ushort* __restrict__ eimg,
                                            ushort* __restrict__ yimg) {
    __shared__ ushort lds[32768];  // 64 KiB
    const int bi = blockIdx.x;
    const int hbase = blockIdx.y * 64;
    const int t = threadIdx.x;

    // E hi+lo: straight 32 KiB copy (image is pre-swizzled).
    {
        const uint4* esrc = (const uint4*)eimg;
        uint4* edst = (uint4*)lds;
        for (int i = t; i < 2048; i += 256) edst[i] = esrc[i];
    }

    // x tile: load fp32, split into bf16 hi/lo, swizzled LDS write.
    const float* xp = x + (size_t)bi * 16384 + (size_t)hbase * 128;
    for (int i = 0; i < 4; i++) {
        int idx = i * 2048 + t * 8;          // element in [64 rows][128 w]
        int row = idx >> 7, w0 = idx & 127;
        float4 v0 = *(const float4*)&xp[idx];
        float4 v1 = *(const float4*)&xp[idx + 4];
        float vv[8] = {v0.x, v0.y, v0.z, v0.w, v1.x, v1.y, v1.z, v1.w};
        ushort h[8], l[8];
#pragma unroll
        for (int j = 0; j < 8; j++) {
            h[j] = f2bf(vv[j]);
            l[j] = f2bf(vv[j] - bf2f(h[j]));
        }
        uint4 hp, lp;
        hp.x = (uint)h[0] | ((uint)h[1] << 16);
        hp.y = (uint)h[2] | ((uint)h[3] << 16);
        hp.z = (uint)h[4] | ((uint)h[5] << 16);
        hp.w = (uint)h[6] | ((uint)h[7] << 16);
        lp.x = (uint)l[0] | ((uint)l[1] << 16);
        lp.y = (uint)l[2] | ((uint)l[3] << 16);
        lp.z = (uint)l[4] | ((uint)l[5] << 16);
        lp.w = (uint)l[6] | ((uint)l[7] << 16);
        int ui = row * 128 + (w0 ^ ((row & 7) << 3));
        *(uint4*)&lds[16384 + ui] = hp;
        *(uint4*)&lds[24576 + ui] = lp;
    }
    __syncthreads();

    const int lane = t & 63, wid = t >> 6;  // wid = row-tile
    const int ln = lane & 15, kq = lane >> 4;
    f32x4 acc[4] = {};
#pragma unroll
    for (int kk = 0; kk < 4; kk++) {
        int k0 = kk * 32 + kq * 8;
        int arow = wid * 16 + ln;
        int aui = arow * 128 + (k0 ^ ((arow & 7) << 3));
        bf16x8 ah = *(bf16x8*)&lds[16384 + aui];
        bf16x8 al = *(bf16x8*)&lds[24576 + aui];
#pragma unroll
        for (int nt = 0; nt < 4; nt++) {
            int col = nt * 16 + ln;
            int bui = col * 128 + (k0 ^ ((col & 7) << 3));
            bf16x8 bh = *(bf16x8*)&lds[bui];
            bf16x8 bl = *(bf16x8*)&lds[8192 + bui];
            acc[nt] = __builtin_amdgcn_mfma_f32_16x16x32_bf16(ah, bh, acc[nt], 0, 0, 0);
            acc[nt] = __builtin_amdgcn_mfma_f32_16x16x32_bf16(ah, bl, acc[nt], 0, 0, 0);
            acc[nt] = __builtin_amdgcn_mfma_f32_16x16x32_bf16(al, bh, acc[nt], 0, 0, 0);
        }
    }

    // C layout: row=(lane>>4)*4+r (h-local), col=lane&15 -> (c,ky).
    // Store split-bf16 into Yimg planes [p][ky][h] swizzled; lane's 4 rows are
    // h-consecutive (4-aligned), XOR only touches h bits 3..5 -> ushort4 store.
    ushort* yp = yimg + (size_t)bi * 16384;
    const int h0 = hbase + wid * 16 + kq * 4;
#pragma unroll
    for (int nt = 0; nt < 4; nt++) {
        int col = nt * 16 + ln;
        int ky = col & 31, c = col >> 5;
        ushort4 h4, l4;
        float v0 = acc[nt][0], v1 = acc[nt][1], v2 = acc[nt][2], v3 = acc[nt][3];
        h4.x = f2bf(v0); l4.x = f2bf(v0 - bf2f(h4.x));
        h4.y = f2bf(v1); l4.y = f2bf(v1 - bf2f(h4.y));
        h4.z = f2bf(v2); l4.z = f2bf(v2 - bf2f(h4.z));
        h4.w = f2bf(v3); l4.w = f2bf(v3 - bf2f(h4.w));
        int hs = h0 ^ ((ky & 7) << 3);
        *(ushort4*)&yp[(c * 2) * 4096 + ky * 128 + hs] = h4;
        *(ushort4*)&yp[(c * 2 + 1) * 4096 + ky * 128 + hs] = l4;
    }
}

// ---------------- Stage F2 (MFMA): Yimg -> Xf (col DFT over H, 64 modes) -----
// Per bi: Xf[64 kxi][32 ky] = E2[64][128] @ Y[128][32] (complex) as 4 real
// GEMMs P1=Er*Yr P2=Ei*Yi P3=Er*Yi P4=Ei*Yr; Xr=P1-P2, Xi=P3+P4.
// 256 blocks x 8 waves; wave=(mt,nt) owns 16(kxi) x 16(ky) tile.
// E2 fragments live in REGISTERS (staged once via LDS, reused over 8 bi);
// LDS (64 KiB static) is then reused as the Y double-buffer (2 x 32 KiB).
__global__ __launch_bounds__(512) void k_f2(const ushort* __restrict__ yimg,
                                            const ushort* __restrict__ e2img,
                                            float2* __restrict__ xf) {
    __shared__ ushort lds[32768];  // 64 KiB
    const int t = threadIdx.x;
    const int bi0 = blockIdx.x * 8;

    // Issue Y[bi0] global loads early; latency hides under E2 setup.
    uint4 R[4];
    {
        const uint4* ys = (const uint4*)(yimg + (size_t)bi0 * 16384);
#pragma unroll
        for (int c = 0; c < 4; c++) R[c] = ys[c * 512 + t];
    }
    // Stage E2 (64 KiB) into LDS (coalesced), pull per-wave fragments to regs.
    {
        const uint4* es = (const uint4*)e2img;
        uint4* ed = (uint4*)lds;
        for (int i = t; i < 4096; i += 512) ed[i] = es[i];
    }
    __syncthreads();
    const int lane = t & 63, wid = t >> 6;
    const int ln = lane & 15, kq = lane >> 4;
    const int mt = wid >> 1, nt = wid & 1;
    const int arow = mt * 16 + ln;   // kxi row (A-operand)
    const int bcol = nt * 16 + ln;   // ky col (B-operand)
    bf16x8 Erh[4], Erl[4], Eih[4], Eil[4];
#pragma unroll
    for (int kk = 0; kk < 4; kk++) {
        int k0 = kk * 32 + kq * 8;
        int ao = arow * 128 + (k0 ^ ((arow & 7) << 3));
        Erh[kk] = *(const bf16x8*)&lds[ao];
        Erl[kk] = *(const bf16x8*)&lds[8192 + ao];
        Eih[kk] = *(const bf16x8*)&lds[16384 + ao];
        Eil[kk] = *(const bf16x8*)&lds[24576 + ao];
    }
    __syncthreads();  // all waves done reading E2 before Y overwrites LDS
    // Write Y[bi0] into buf0.
    {
        uint4* yd = (uint4*)lds;
#pragma unroll
        for (int c = 0; c < 4; c++) yd[c * 512 + t] = R[c];
    }
    __syncthreads();

    int cur = 0;
    for (int j = 0; j < 8; j++) {
        const int bi = bi0 + j;
        if (j < 7) {  // issue next-tile loads; HBM latency hides under MFMA
            const uint4* ys = (const uint4*)(yimg + (size_t)(bi + 1) * 16384);
#pragma unroll
            for (int c = 0; c < 4; c++) R[c] = ys[c * 512 + t];
        }
        const ushort* yb = &lds[cur * 16384];
        f32x4 P1 = {}, P2 = {}, P3 = {}, P4 = {};
#pragma unroll
        for (int kk = 0; kk < 4; kk++) {
            int k0 = kk * 32 + kq * 8;
            int bo = bcol * 128 + (k0 ^ ((bcol & 7) << 3));
            bf16x8 Yrh = *(const bf16x8*)&yb[bo];
            bf16x8 Yrl = *(const bf16x8*)&yb[4096 + bo];
            bf16x8 Yih = *(const bf16x8*)&yb[8192 + bo];
            bf16x8 Yil = *(const bf16x8*)&yb[12288 + bo];
            P1 = __builtin_amdgcn_mfma_f32_16x16x32_bf16(Erh[kk], Yrh, P1, 0, 0, 0);
            P1 = __builtin_amdgcn_mfma_f32_16x16x32_bf16(Erh[kk], Yrl, P1, 0, 0, 0);
            P1 = __builtin_amdgcn_mfma_f32_16x16x32_bf16(Erl[kk], Yrh, P1, 0, 0, 0);
            P2 = __builtin_amdgcn_mfma_f32_16x16x32_bf16(Eih[kk], Yih, P2, 0, 0, 0);
            P2 = __builtin_amdgcn_mfma_f32_16x16x32_bf16(Eih[kk], Yil, P2, 0, 0, 0);
            P2 = __builtin_amdgcn_mfma_f32_16x16x32_bf16(Eil[kk], Yih, P2, 0, 0, 0);
            P3 = __builtin_amdgcn_mfma_f32_16x16x32_bf16(Erh[kk], Yih, P3, 0, 0, 0);
            P3 = __builtin_amdgcn_mfma_f32_16x16x32_bf16(Erh[kk], Yil, P3, 0, 0, 0);
            P3 = __builtin_amdgcn_mfma_f32_16x16x32_bf16(Erl[kk], Yih, P3, 0, 0, 0);
            P4 = __builtin_amdgcn_mfma_f32_16x16x32_bf16(Eih[kk], Yrh, P4, 0, 0, 0);
            P4 = __builtin_amdgcn_mfma_f32_16x16x32_bf16(Eih[kk], Yrl, P4, 0, 0, 0);
            P4 = __builtin_amdgcn_mfma_f32_16x16x32_bf16(Eil[kk], Yrh, P4, 0, 0, 0);
        }
        // C layout: row = kq*4+r (kxi-local), col = ln (ky-local).
        float2* xp = xf + (size_t)bi * 2048 + (size_t)(mt * 16 + kq * 4) * 32 + bcol;
#pragma unroll
        for (int r = 0; r < 4; r++)
            xp[(size_t)r * 32] = make_float2(P1[r] - P2[r], P3[r] + P4[r]);
        if (j < 7) {
            // buf[cur^1]'s readers all passed the barrier at end of iter j-1.
            uint4* yd = (uint4*)&lds[(cur ^ 1) * 16384];
#pragma unroll
            for (int c = 0; c < 4; c++) yd[c * 512 + t] = R[c];
            __syncthreads();
            cur ^= 1;
        }
    }
}

// ---------------- Stage M: channel mix, T = Xf @ conj(W) ----------------
__global__ __launch_bounds__(512) void k_mix(const float2* __restrict__ xf,
                                             const float* __restrict__ w1r, const float* __restrict__ w1i,
                                             const float* __restrict__ w2r, const float* __restrict__ w2i,
                                             float2* __restrict__ tt) {
    __shared__ float2 xfs[8192];  // [8 b][32 i][32 ky] per stage, 64 KiB
    const int kxi = blockIdx.x;       // 0..63
    const int b0 = blockIdx.y * 8;    // 4 groups of 8 b
    const int t = threadIdx.x;
    const int ky = t & 31, grp = t >> 5;  // grp 0..15
    const int o0 = grp * 4;
    const float* wr = (kxi < 32) ? w1r : w2r;
    const float* wi = (kxi < 32) ? w1i : w2i;
    const int kxim = kxi & 31;
    float accr[8][4], acci[8][4];
    for (int jb = 0; jb < 8; jb++)
        for (int jo = 0; jo < 4; jo++) { accr[jb][jo] = 0.0f; acci[jb][jo] = 0.0f; }

    for (int stage = 0; stage < 2; stage++) {
        const int ibase = stage * 32;
        __syncthreads();
        for (int idx = t; idx < 8192; idx += 512) {
            int b = idx >> 10, ii = (idx >> 5) & 31, kk = idx & 31;
            size_t g = ((size_t)(b0 + b) * 64 + (ibase + ii)) * 2048 + (size_t)kxi * 32 + kk;
            xfs[idx] = xf[g];
        }
        __syncthreads();
        for (int ii = 0; ii < 32; ii++) {
            const int i = ibase + ii;
            float wr4[4], wi4[4];
#pragma unroll
            for (int jo = 0; jo < 4; jo++) {
                size_t g = ((size_t)i * 64 + (o0 + jo)) * 1024 + (size_t)kxim * 32 + ky;
                wr4[jo] = wr[g]; wi4[jo] = wi[g];
            }
#pragma unroll
            for (int jb = 0; jb < 8; jb++) {
                float2 xv = xfs[(jb << 10) + (ii << 5) + ky];
#pragma unroll
                for (int jo = 0; jo < 4; jo++) {
                    accr[jb][jo] += xv.x * wr4[jo] + xv.y * wi4[jo];
                    acci[jb][jo] += xv.y * wr4[jo] - xv.x * wi4[jo];
                }
            }
        }
    }
    for (int jb = 0; jb < 8; jb++)
        for (int jo = 0; jo < 4; jo++) {
            size_t g = ((size_t)(b0 + jb) * 64 + (o0 + jo)) * 2048 + (size_t)kxi * 32 + ky;
            tt[g] = make_float2(accr[jb][jo], acci[jb][jo]);
        }
}

// ---------------- Stage I1: T -> Z (inverse DFT over ky -> 65 cols) ----------------
__global__ __launch_bounds__(256) void k_i1(const float2* __restrict__ tt,
                                            float2* __restrict__ z) {
    __shared__ float2 ts[2048];  // [kxi][ky], 16 KiB
    const int bo = blockIdx.x, t = threadIdx.x;
    const float2* tp = tt + (size_t)bo * 2048;
    for (int idx = t; idx < 2048; idx += 256) ts[idx] = tp[idx];
    __syncthreads();
    float2* zp = z + (size_t)bo * 4160;
    for (int p = t; p < 2080; p += 256) {
        int w = p % 65, kxi = p / 65;  // kxi 0..31, paired with kxi+32
        float dc, ds;
        sincosf(PI2 * (float)w / 65.0f, &ds, &dc);
        float c = 1.0f, s = 0.0f;
        float z1r = 0, z1i = 0, z2r = 0, z2i = 0;
        for (int ky = 0; ky < 32; ky++) {
            float2 t1 = ts[kxi * 32 + ky];
            float2 t2 = ts[(kxi + 32) * 32 + ky];
            z1r += t1.x * c - t1.y * s;
            z1i += t1.x * s + t1.y * c;
            z2r += t2.x * c - t2.y * s;
            z2i += t2.x * s + t2.y * c;
            float nc = c * dc - s * ds;
            s = s * dc + c * ds;
            c = nc;
        }
        zp[kxi * 65 + w] = make_float2(z1r, z1i);
        zp[(kxi + 32) * 65 + w] = make_float2(z2r, z2i);
    }
}

// ---------------- Stage I2: Z -> out (inverse DFT over H, real part) ----------------
// Row pairing: slot kxi (row kxi) and slot kxi+32 (row kxi+96).
// e^{2pi i * 96 h/128} = (-i)^h, so A(h) = Z1 + (-i)^h * Z2, out = Re(e^{2pi i kxi h/128} * A).
__global__ __launch_bounds__(256) void k_i2(const float2* __restrict__ z,
                                            float* __restrict__ out) {
    __shared__ float2 zs[64 * 68];  // [kxi][w'], padded to 68 (zero pad cols 65..67)
    const int bo = blockIdx.x, t = threadIdx.x;
    const float2* zp = z + (size_t)bo * 4160;
    for (int idx = t; idx < 64 * 68; idx += 256) {
        int kxi = idx / 68, w = idx % 68;
        float2 v = make_float2(0.0f, 0.0f);
        if (w < 65) v = zp[kxi * 65 + w];
        zs[idx] = v;
    }
    __syncthreads();
    float* op = out + (size_t)bo * 8320;
    const float scale = 1.0f / 8320.0f;  // 1/(128*65)
    for (int tile = t; tile < 544; tile += 256) {  // 32 hg * 17 wg
        int hg = tile / 17, wg = tile % 17;
        int h0 = hg * 4, w0 = wg * 4;
        float c[4], s[4], dc[4], ds[4], acc[4][4];
        for (int j = 0; j < 4; j++) {
            sincosf(PI2 * (float)(h0 + j) / 128.0f, &ds[j], &dc[j]);
            c[j] = 1.0f; s[j] = 0.0f;
            for (int k = 0; k < 4; k++) acc[j][k] = 0.0f;
        }
        for (int kxi = 0; kxi < 32; kxi++) {
            float2 z1[4], z2[4];
            const float2* p1 = &zs[kxi * 68 + w0];
            const float2* p2 = &zs[(kxi + 32) * 68 + w0];
#pragma unroll
            for (int k = 0; k < 4; k++) { z1[k] = p1[k]; z2[k] = p2[k]; }
#pragma unroll
            for (int k = 0; k < 4; k++) {
                float a0r = z1[k].x + z2[k].x, a0i = z1[k].y + z2[k].y;   // h%4==0: +Z2
                float a1r = z1[k].x + z2[k].y, a1i = z1[k].y - z2[k].x;   // h%4==1: -i*Z2
                float a2r = z1[k].x - z2[k].x, a2i = z1[k].y - z2[k].y;   // h%4==2: -Z2
                float a3r = z1[k].x - z2[k].y, a3i = z1[k].y + z2[k].x;   // h%4==3: +i*Z2
                acc[0][k] += c[0] * a0r - s[0] * a0i;
                acc[1][k] += c[1] * a1r - s[1] * a1i;
                acc[2][k] += c[2] * a2r - s[2] * a2i;
                acc[3][k] += c[3] * a3r - s[3] * a3i;
            }
#pragma unroll
            for (int j = 0; j < 4; j++) {
                float nc = c[j] * dc[j] - s[j] * ds[j];
                s[j] = s[j] * dc[j] + c[j] * ds[j];
                c[j] = nc;
            }
        }
        for (int j = 0; j < 4; j++)
            for (int k = 0; k < 4; k++) {
                int w = w0 + k;
                if (w < 65) op[(h0 + j) * 65 + w] = acc[j][k] * scale;
            }
    }
}

extern "C" void kernel_launch(void* const* d_in, const int* in_sizes, int n_in,
                              void* d_out, int out_size, void* d_ws, size_t ws_size,
                              hipStream_t stream) {
    const float* x   = (const float*)d_in[0];
    const float* w1r = (const float*)d_in[1];
    const float* w1i = (const float*)d_in[2];
    const float* w2r = (const float*)d_in[3];
    const float* w2i = (const float*)d_in[4];
    float2* ws = (float2*)d_ws;

    // buf1 [0, 8388608) f2: Yimg (bf16 planes, 64 MB) then T.
    // buf2 [8388608, 16908288) f2: Xf [0,4194304) then Z [0,8519680).
    // E images live in buf2 slack after Xf: consumed by f1/f2, overwritten by Z
    // at i1 (after use); re-initialized every launch.
    ushort* yimg = (ushort*)ws;
    float2* ta   = ws;
    float2* xfa  = ws + 8388608;
    float2* za   = ws + 8388608;
    ushort* e1img = (ushort*)(ws + 8388608 + 4194304);          // 32 KiB
    ushort* e2img = (ushort*)(ws + 8388608 + 4194304 + 4096);   // 64 KiB
    float* out = (float*)d_out;

    k_einit<<<64, 256, 0, stream>>>(e1img, e2img);
    k_f1<<<dim3(2048, 2), 256, 0, stream>>>(x, e1img, yimg);
    k_f2<<<256, 512, 0, stream>>>(yimg, e2img, xfa);
    k_mix<<<dim3(64, 4), 512, 0, stream>>>(xfa, w1r, w1i, w2r, w2i, ta);
    k_i1<<<2048, 256, 0, stream>>>(ta, za);
    k_i2<<<2048, 256, 0, stream>>>(za, out);
}

// Round 4
// 401.216 us; speedup vs baseline: 1.6018x; 1.3060x over previous
//
#include <hip/hip_runtime.h>
#include <math.h>

#define PI2 6.28318530717958647692f

// Problem constants: B=32, CI=CO=64, H=W=128, M1=M2=32.
// Intermediates:
//   Yimg [bi=2048][p=4][ky=32][h=128] ushort (bf16 planes: rh,rl,ih,il; swizzled)  (buf1, 64 MB)
//   Xf   [bi=2048][kxi=64][ky=32] float2   (buf2)
//   T    [bo=2048][kxi=64][ky=32] float2   (buf1, overwrites Yimg after f2)
// out [b=32][o=64][h=128][w'=65] fp32  (written directly by fused k_inv)
// Swizzle (bf16 LDS images, granule = 8 ushorts): idx = row*S + (oct ^ f(row))*8 + j

typedef short bf16x8 __attribute__((ext_vector_type(8)));
typedef float f32x4 __attribute__((ext_vector_type(4)));

static __device__ __forceinline__ ushort f2bf(float f) {
    uint u = __float_as_uint(f);
    u += 0x7FFFu + ((u >> 16) & 1u);  // round-to-nearest-even
    return (ushort)(u >> 16);
}
static __device__ __forceinline__ float bf2f(ushort h) {
    return __uint_as_float(((uint)h) << 16);
}

// ---------------- Twiddle init: E1, E2, EC, EW images ------------------------
// E1 (ushort idx): hi [0,8192): col*128 + (w ^ ((col&7)<<3)); lo [8192,16384).
// E2: 4 planes x [kxi=64][h=128]: Er-hi, Er-lo, Ei-hi, Ei-lo (swizzled).
// EC (GEMM2 A, fragment-ordered): idx = (((mt*4+kk)*4+kq)*16+ln)*8+j, hi then lo
//   at +16384. Element (h=mt*16+ln, k=kk*32+kq*8+j):
//   k<64: cos(2pi kx(k) h/128)/8320 ; k>=64: sin(2pi kx(k-64) h/128)/8320.
// EW (GEMM1 B, fragment-ordered): 6 planes x 2560: Cw-h,Cw-l,Sw-h,Sw-l,Sn-h,Sn-l
//   off = ((nt1*4+kq)*16+ln)*8+j -> (ky=kq*8+j, w=nt1*16+ln); w>=65 -> 0.
__global__ void k_einit(ushort* __restrict__ e1, ushort* __restrict__ e2,
                        ushort* __restrict__ ec, ushort* __restrict__ ew) {
    int id = blockIdx.x * 256 + threadIdx.x;
    if (id < 8192) {
        int w = id & 127, col = id >> 7;
        int ky = col & 31, csel = col >> 5;
        int m = (ky * w) & 127;
        float sv, cv;
        sincosf((float)m * (PI2 / 128.0f), &sv, &cv);
        float val = csel ? -sv : cv;
        ushort hi = f2bf(val);
        int ui = col * 128 + (w ^ ((col & 7) << 3));
        e1[ui] = hi;
        e1[8192 + ui] = f2bf(val - bf2f(hi));
    } else if (id < 16384) {
        int id2 = id - 8192;
        int h = id2 & 127, kxi = id2 >> 7;
        int kx = (kxi < 32) ? kxi : (kxi + 64);
        int m = (kx * h) & 127;
        float sv, cv;
        sincosf((float)m * (PI2 / 128.0f), &sv, &cv);
        float er = cv, ei = -sv;
        int ui = kxi * 128 + (h ^ ((kxi & 7) << 3));
        ushort eh = f2bf(er);
        e2[ui] = eh;
        e2[8192 + ui] = f2bf(er - bf2f(eh));
        ushort ih = f2bf(ei);
        e2[16384 + ui] = ih;
        e2[24576 + ui] = f2bf(ei - bf2f(ih));
    } else if (id < 32768) {
        int id2 = id - 16384;
        int j = id2 & 7, ln = (id2 >> 3) & 15, kq = (id2 >> 7) & 3,
            kk = (id2 >> 9) & 3, mt = id2 >> 11;
        int h = mt * 16 + ln;
        int k = kk * 32 + kq * 8 + j;
        int kc = (k < 64) ? k : (k - 64);
        int kx = (kc < 32) ? kc : (kc + 64);
        int m = (kx * h) & 127;
        float sv, cv;
        sincosf((float)m * (PI2 / 128.0f), &sv, &cv);
        float val = ((k < 64) ? cv : sv) * (1.0f / 8320.0f);
        ushort hi = f2bf(val);
        ec[id2] = hi;
        ec[16384 + id2] = f2bf(val - bf2f(hi));
    } else if (id < 40448) {
        int id3 = id - 32768;
        int off = id3 % 2560, pe = id3 / 2560;   // pe 0=Cw 1=Sw 2=-Sw
        int j = off & 7, ln = (off >> 3) & 15, kq = (off >> 7) & 3, nt1 = off >> 9;
        int ky = kq * 8 + j, w = nt1 * 16 + ln;
        float val = 0.0f;
        if (w < 65) {
            int m = (w * ky) % 65;
            float sv, cv;
            sincosf((float)m * (PI2 / 65.0f), &sv, &cv);
            val = (pe == 0) ? cv : ((pe == 1) ? sv : -sv);
        }
        ushort hi = f2bf(val);
        ew[pe * 5120 + off] = hi;
        ew[pe * 5120 + 2560 + off] = f2bf(val - bf2f(hi));
    }
}

// ---------------- Stage F1 (MFMA): x -> Yimg (row DFT over W, 32 modes) ------
__global__ __launch_bounds__(256) void k_f1(const float* __restrict__ x,
                                            const ushort* __restrict__ eimg,
                                            ushort* __restrict__ yimg) {
    __shared__ ushort lds[32768];  // 64 KiB
    const int bi = blockIdx.x;
    const int hbase = blockIdx.y * 64;
    const int t = threadIdx.x;

    {
        const uint4* esrc = (const uint4*)eimg;
        uint4* edst = (uint4*)lds;
        for (int i = t; i < 2048; i += 256) edst[i] = esrc[i];
    }

    const float* xp = x + (size_t)bi * 16384 + (size_t)hbase * 128;
    for (int i = 0; i < 4; i++) {
        int idx = i * 2048 + t * 8;
        int row = idx >> 7, w0 = idx & 127;
        float4 v0 = *(const float4*)&xp[idx];
        float4 v1 = *(const float4*)&xp[idx + 4];
        float vv[8] = {v0.x, v0.y, v0.z, v0.w, v1.x, v1.y, v1.z, v1.w};
        ushort h[8], l[8];
#pragma unroll
        for (int j = 0; j < 8; j++) {
            h[j] = f2bf(vv[j]);
            l[j] = f2bf(vv[j] - bf2f(h[j]));
        }
        uint4 hp, lp;
        hp.x = (uint)h[0] | ((uint)h[1] << 16);
        hp.y = (uint)h[2] | ((uint)h[3] << 16);
        hp.z = (uint)h[4] | ((uint)h[5] << 16);
        hp.w = (uint)h[6] | ((uint)h[7] << 16);
        lp.x = (uint)l[0] | ((uint)l[1] << 16);
        lp.y = (uint)l[2] | ((uint)l[3] << 16);
        lp.z = (uint)l[4] | ((uint)l[5] << 16);
        lp.w = (uint)l[6] | ((uint)l[7] << 16);
        int ui = row * 128 + (w0 ^ ((row & 7) << 3));
        *(uint4*)&lds[16384 + ui] = hp;
        *(uint4*)&lds[24576 + ui] = lp;
    }
    __syncthreads();

    const int lane = t & 63, wid = t >> 6;
    const int ln = lane & 15, kq = lane >> 4;
    f32x4 acc[4] = {};
#pragma unroll
    for (int kk = 0; kk < 4; kk++) {
        int k0 = kk * 32 + kq * 8;
        int arow = wid * 16 + ln;
        int aui = arow * 128 + (k0 ^ ((arow & 7) << 3));
        bf16x8 ah = *(bf16x8*)&lds[16384 + aui];
        bf16x8 al = *(bf16x8*)&lds[24576 + aui];
#pragma unroll
        for (int nt = 0; nt < 4; nt++) {
            int col = nt * 16 + ln;
            int bui = col * 128 + (k0 ^ ((col & 7) << 3));
            bf16x8 bh = *(bf16x8*)&lds[bui];
            bf16x8 bl = *(bf16x8*)&lds[8192 + bui];
            acc[nt] = __builtin_amdgcn_mfma_f32_16x16x32_bf16(ah, bh, acc[nt], 0, 0, 0);
            acc[nt] = __builtin_amdgcn_mfma_f32_16x16x32_bf16(ah, bl, acc[nt], 0, 0, 0);
            acc[nt] = __builtin_amdgcn_mfma_f32_16x16x32_bf16(al, bh, acc[nt], 0, 0, 0);
        }
    }

    ushort* yp = yimg + (size_t)bi * 16384;
    const int h0 = hbase + wid * 16 + kq * 4;
#pragma unroll
    for (int nt = 0; nt < 4; nt++) {
        int col = nt * 16 + ln;
        int ky = col & 31, c = col >> 5;
        ushort4 h4, l4;
        float v0 = acc[nt][0], v1 = acc[nt][1], v2 = acc[nt][2], v3 = acc[nt][3];
        h4.x = f2bf(v0); l4.x = f2bf(v0 - bf2f(h4.x));
        h4.y = f2bf(v1); l4.y = f2bf(v1 - bf2f(h4.y));
        h4.z = f2bf(v2); l4.z = f2bf(v2 - bf2f(h4.z));
        h4.w = f2bf(v3); l4.w = f2bf(v3 - bf2f(h4.w));
        int hs = h0 ^ ((ky & 7) << 3);
        *(ushort4*)&yp[(c * 2) * 4096 + ky * 128 + hs] = h4;
        *(ushort4*)&yp[(c * 2 + 1) * 4096 + ky * 128 + hs] = l4;
    }
}

// ---------------- Stage F2 (MFMA): Yimg -> Xf (col DFT over H, 64 modes) -----
__global__ __launch_bounds__(512) void k_f2(const ushort* __restrict__ yimg,
                                            const ushort* __restrict__ e2img,
                                            float2* __restrict__ xf) {
    __shared__ ushort lds[32768];  // 64 KiB
    const int t = threadIdx.x;
    const int bi0 = blockIdx.x * 8;

    uint4 R[4];
    {
        const uint4* ys = (const uint4*)(yimg + (size_t)bi0 * 16384);
#pragma unroll
        for (int c = 0; c < 4; c++) R[c] = ys[c * 512 + t];
    }
    {
        const uint4* es = (const uint4*)e2img;
        uint4* ed = (uint4*)lds;
        for (int i = t; i < 4096; i += 512) ed[i] = es[i];
    }
    __syncthreads();
    const int lane = t & 63, wid = t >> 6;
    const int ln = lane & 15, kq = lane >> 4;
    const int mt = wid >> 1, nt = wid & 1;
    const int arow = mt * 16 + ln;
    const int bcol = nt * 16 + ln;
    bf16x8 Erh[4], Erl[4], Eih[4], Eil[4];
#pragma unroll
    for (int kk = 0; kk < 4; kk++) {
        int k0 = kk * 32 + kq * 8;
        int ao = arow * 128 + (k0 ^ ((arow & 7) << 3));
        Erh[kk] = *(const bf16x8*)&lds[ao];
        Erl[kk] = *(const bf16x8*)&lds[8192 + ao];
        Eih[kk] = *(const bf16x8*)&lds[16384 + ao];
        Eil[kk] = *(const bf16x8*)&lds[24576 + ao];
    }
    __syncthreads();
    {
        uint4* yd = (uint4*)lds;
#pragma unroll
        for (int c = 0; c < 4; c++) yd[c * 512 + t] = R[c];
    }
    __syncthreads();

    int cur = 0;
    for (int j = 0; j < 8; j++) {
        const int bi = bi0 + j;
        if (j < 7) {
            const uint4* ys = (const uint4*)(yimg + (size_t)(bi + 1) * 16384);
#pragma unroll
            for (int c = 0; c < 4; c++) R[c] = ys[c * 512 + t];
        }
        const ushort* yb = &lds[cur * 16384];
        f32x4 P1 = {}, P2 = {}, P3 = {}, P4 = {};
#pragma unroll
        for (int kk = 0; kk < 4; kk++) {
            int k0 = kk * 32 + kq * 8;
            int bo = bcol * 128 + (k0 ^ ((bcol & 7) << 3));
            bf16x8 Yrh = *(const bf16x8*)&yb[bo];
            bf16x8 Yrl = *(const bf16x8*)&yb[4096 + bo];
            bf16x8 Yih = *(const bf16x8*)&yb[8192 + bo];
            bf16x8 Yil = *(const bf16x8*)&yb[12288 + bo];
            P1 = __builtin_amdgcn_mfma_f32_16x16x32_bf16(Erh[kk], Yrh, P1, 0, 0, 0);
            P1 = __builtin_amdgcn_mfma_f32_16x16x32_bf16(Erh[kk], Yrl, P1, 0, 0, 0);
            P1 = __builtin_amdgcn_mfma_f32_16x16x32_bf16(Erl[kk], Yrh, P1, 0, 0, 0);
            P2 = __builtin_amdgcn_mfma_f32_16x16x32_bf16(Eih[kk], Yih, P2, 0, 0, 0);
            P2 = __builtin_amdgcn_mfma_f32_16x16x32_bf16(Eih[kk], Yil, P2, 0, 0, 0);
            P2 = __builtin_amdgcn_mfma_f32_16x16x32_bf16(Eil[kk], Yih, P2, 0, 0, 0);
            P3 = __builtin_amdgcn_mfma_f32_16x16x32_bf16(Erh[kk], Yih, P3, 0, 0, 0);
            P3 = __builtin_amdgcn_mfma_f32_16x16x32_bf16(Erh[kk], Yil, P3, 0, 0, 0);
            P3 = __builtin_amdgcn_mfma_f32_16x16x32_bf16(Erl[kk], Yih, P3, 0, 0, 0);
            P4 = __builtin_amdgcn_mfma_f32_16x16x32_bf16(Eih[kk], Yrh, P4, 0, 0, 0);
            P4 = __builtin_amdgcn_mfma_f32_16x16x32_bf16(Eih[kk], Yrl, P4, 0, 0, 0);
            P4 = __builtin_amdgcn_mfma_f32_16x16x32_bf16(Eil[kk], Yrh, P4, 0, 0, 0);
        }
        float2* xp = xf + (size_t)bi * 2048 + (size_t)(mt * 16 + kq * 4) * 32 + bcol;
#pragma unroll
        for (int r = 0; r < 4; r++)
            xp[(size_t)r * 32] = make_float2(P1[r] - P2[r], P3[r] + P4[r]);
        if (j < 7) {
            uint4* yd = (uint4*)&lds[(cur ^ 1) * 16384];
#pragma unroll
            for (int c = 0; c < 4; c++) yd[c * 512 + t] = R[c];
            __syncthreads();
            cur ^= 1;
        }
    }
}

// ---------------- Stage M: channel mix, T = Xf @ conj(W) ----------------
__global__ __launch_bounds__(512) void k_mix(const float2* __restrict__ xf,
                                             const float* __restrict__ w1r, const float* __restrict__ w1i,
                                             const float* __restrict__ w2r, const float* __restrict__ w2i,
                                             float2* __restrict__ tt) {
    __shared__ float2 xfs[8192];  // 64 KiB
    const int kxi = blockIdx.x;
    const int b0 = blockIdx.y * 8;
    const int t = threadIdx.x;
    const int ky = t & 31, grp = t >> 5;
    const int o0 = grp * 4;
    const float* wr = (kxi < 32) ? w1r : w2r;
    const float* wi = (kxi < 32) ? w1i : w2i;
    const int kxim = kxi & 31;
    float accr[8][4], acci[8][4];
    for (int jb = 0; jb < 8; jb++)
        for (int jo = 0; jo < 4; jo++) { accr[jb][jo] = 0.0f; acci[jb][jo] = 0.0f; }

    for (int stage = 0; stage < 2; stage++) {
        const int ibase = stage * 32;
        __syncthreads();
        for (int idx = t; idx < 8192; idx += 512) {
            int b = idx >> 10, ii = (idx >> 5) & 31, kk = idx & 31;
            size_t g = ((size_t)(b0 + b) * 64 + (ibase + ii)) * 2048 + (size_t)kxi * 32 + kk;
            xfs[idx] = xf[g];
        }
        __syncthreads();
        for (int ii = 0; ii < 32; ii++) {
            const int i = ibase + ii;
            float wr4[4], wi4[4];
#pragma unroll
            for (int jo = 0; jo < 4; jo++) {
                size_t g = ((size_t)i * 64 + (o0 + jo)) * 1024 + (size_t)kxim * 32 + ky;
                wr4[jo] = wr[g]; wi4[jo] = wi[g];
            }
#pragma unroll
            for (int jb = 0; jb < 8; jb++) {
                float2 xv = xfs[(jb << 10) + (ii << 5) + ky];
#pragma unroll
                for (int jo = 0; jo < 4; jo++) {
                    accr[jb][jo] += xv.x * wr4[jo] + xv.y * wi4[jo];
                    acci[jb][jo] += xv.y * wr4[jo] - xv.x * wi4[jo];
                }
            }
        }
    }
    for (int jb = 0; jb < 8; jb++)
        for (int jo = 0; jo < 4; jo++) {
            size_t g = ((size_t)(b0 + jb) * 64 + (o0 + jo)) * 2048 + (size_t)kxi * 32 + ky;
            tt[g] = make_float2(accr[jb][jo], acci[jb][jo]);
        }
}

// ---------------- Stage INV (MFMA, fused I1+I2): T -> out --------------------
// Per bo: GEMM1: Z[64 kxi][80 w] = T[64][32] @ Ew[32][80] (complex, split-bf16)
//   zr = Tr@Cw + Ti@(-Sw); zi = Tr@Sw + Ti@Cw.
// Zcat[128 k][80 w] = [zr ; -zi] -> LDS bf16 hi/lo planes [w][k] (oct ^(w&7)).
// GEMM2: out[128 h][65 w] = EC[128h][128k] @ Zcat (scale 1/8320 folded in EC).
// 512 thr (8 waves). LDS 40 KiB: T-planes [0,10240) us phase1; Zcat hi [0,10240)
// lo [10240,20480) phase2 (zr/zi carried in regs across the reuse).
#define G1_TILE(TT, ZRv, ZIv)                                                  \
    do {                                                                       \
        int mt1_ = (TT) & 3, nt1_ = (TT) >> 2;                                 \
        int arow_ = mt1_ * 16 + ln;                                            \
        int aad_ = arow_ * 40 + ((kq ^ (arow_ & 3)) << 3);                     \
        bf16x8 TRh_ = *(const bf16x8*)&lds[aad_];                              \
        bf16x8 TRl_ = *(const bf16x8*)&lds[2560 + aad_];                       \
        bf16x8 TIh_ = *(const bf16x8*)&lds[5120 + aad_];                       \
        bf16x8 TIl_ = *(const bf16x8*)&lds[7680 + aad_];                       \
        const ushort* bp_ = ew + (((nt1_ * 4 + kq) * 16 + ln) * 8);            \
        bf16x8 CWh_ = *(const bf16x8*)(bp_);                                   \
        bf16x8 CWl_ = *(const bf16x8*)(bp_ + 2560);                            \
        bf16x8 SWh_ = *(const bf16x8*)(bp_ + 5120);                            \
        bf16x8 SWl_ = *(const bf16x8*)(bp_ + 7680);                            \
        bf16x8 SNh_ = *(const bf16x8*)(bp_ + 10240);                           \
        bf16x8 SNl_ = *(const bf16x8*)(bp_ + 12800);                           \
        ZRv = __builtin_amdgcn_mfma_f32_16x16x32_bf16(TRh_, CWh_, ZRv, 0, 0, 0); \
        ZRv = __builtin_amdgcn_mfma_f32_16x16x32_bf16(TRh_, CWl_, ZRv, 0, 0, 0); \
        ZRv = __builtin_amdgcn_mfma_f32_16x16x32_bf16(TRl_, CWh_, ZRv, 0, 0, 0); \
        ZRv = __builtin_amdgcn_mfma_f32_16x16x32_bf16(TIh_, SNh_, ZRv, 0, 0, 0); \
        ZRv = __builtin_amdgcn_mfma_f32_16x16x32_bf16(TIh_, SNl_, ZRv, 0, 0, 0); \
        ZRv = __builtin_amdgcn_mfma_f32_16x16x32_bf16(TIl_, SNh_, ZRv, 0, 0, 0); \
        ZIv = __builtin_amdgcn_mfma_f32_16x16x32_bf16(TRh_, SWh_, ZIv, 0, 0, 0); \
        ZIv = __builtin_amdgcn_mfma_f32_16x16x32_bf16(TRh_, SWl_, ZIv, 0, 0, 0); \
        ZIv = __builtin_amdgcn_mfma_f32_16x16x32_bf16(TRl_, SWh_, ZIv, 0, 0, 0); \
        ZIv = __builtin_amdgcn_mfma_f32_16x16x32_bf16(TIh_, CWh_, ZIv, 0, 0, 0); \
        ZIv = __builtin_amdgcn_mfma_f32_16x16x32_bf16(TIh_, CWl_, ZIv, 0, 0, 0); \
        ZIv = __builtin_amdgcn_mfma_f32_16x16x32_bf16(TIl_, CWh_, ZIv, 0, 0, 0); \
    } while (0)

#define Z_STORE(TT, ZRv, ZIv)                                                  \
    do {                                                                       \
        int mt1_ = (TT) & 3, nt1_ = (TT) >> 2;                                 \
        int w_ = nt1_ * 16 + ln;                                               \
        int kxi_ = mt1_ * 16 + kq * 4;                                         \
        int octr_ = kxi_ >> 3, sub_ = kxi_ & 7;                                \
        int adr_ = w_ * 128 + ((octr_ ^ (w_ & 7)) << 3) + sub_;                \
        int adi_ = w_ * 128 + (((octr_ + 8) ^ (w_ & 7)) << 3) + sub_;          \
        ushort4 rh_, rl_, ih_, il_;                                            \
        float v0_ = ZRv[0], v1_ = ZRv[1], v2_ = ZRv[2], v3_ = ZRv[3];          \
        rh_.x = f2bf(v0_); rl_.x = f2bf(v0_ - bf2f(rh_.x));                    \
        rh_.y = f2bf(v1_); rl_.y = f2bf(v1_ - bf2f(rh_.y));                    \
        rh_.z = f2bf(v2_); rl_.z = f2bf(v2_ - bf2f(rh_.z));                    \
        rh_.w = f2bf(v3_); rl_.w = f2bf(v3_ - bf2f(rh_.w));                    \
        v0_ = -ZIv[0]; v1_ = -ZIv[1]; v2_ = -ZIv[2]; v3_ = -ZIv[3];            \
        ih_.x = f2bf(v0_); il_.x = f2bf(v0_ - bf2f(ih_.x));                    \
        ih_.y = f2bf(v1_); il_.y = f2bf(v1_ - bf2f(ih_.y));                    \
        ih_.z = f2bf(v2_); il_.z = f2bf(v2_ - bf2f(ih_.z));                    \
        ih_.w = f2bf(v3_); il_.w = f2bf(v3_ - bf2f(ih_.w));                    \
        *(ushort4*)&lds[adr_] = rh_;                                           \
        *(ushort4*)&lds[10240 + adr_] = rl_;                                   \
        *(ushort4*)&lds[adi_] = ih_;                                           \
        *(ushort4*)&lds[10240 + adi_] = il_;                                   \
    } while (0)

__global__ __launch_bounds__(512) void k_inv(const float2* __restrict__ tt,
                                             const ushort* __restrict__ ec,
                                             const ushort* __restrict__ ew,
                                             float* __restrict__ out) {
    __shared__ ushort lds[20480];  // 40 KiB
    const int bo = blockIdx.x, t = threadIdx.x;
    const int lane = t & 63, wid = t >> 6;
    const int ln = lane & 15, kq = lane >> 4;

    // EC A-fragments (GEMM2, const): issue early, used after GEMM1.
    bf16x8 ECh[4], ECl[4];
#pragma unroll
    for (int kk = 0; kk < 4; kk++) {
        const ushort* p = ec + ((((wid * 4 + kk) * 4 + kq) * 16 + ln) * 8);
        ECh[kk] = *(const bf16x8*)p;
        ECl[kk] = *(const bf16x8*)(p + 16384);
    }

    // Stage T -> split-bf16 A-planes [row(64)][stride 40], ky-oct swz ^(row&3).
    const float2* tp = tt + (size_t)bo * 2048;
    for (int i = t; i < 2048; i += 512) {
        float2 v = tp[i];
        int row = i >> 5, ky = i & 31;
        int ad = row * 40 + ((((ky >> 3) ^ (row & 3))) << 3) + (ky & 7);
        ushort rh = f2bf(v.x), ih = f2bf(v.y);
        lds[ad] = rh;
        lds[2560 + ad] = f2bf(v.x - bf2f(rh));
        lds[5120 + ad] = ih;
        lds[7680 + ad] = f2bf(v.y - bf2f(ih));
    }
    __syncthreads();

    // GEMM1: 20 tiles (nt1*4+mt1) over 8 waves, results held in registers.
    f32x4 ZR0 = {}, ZI0 = {}, ZR1 = {}, ZI1 = {}, ZR2 = {}, ZI2 = {};
    G1_TILE(wid, ZR0, ZI0);
    G1_TILE(wid + 8, ZR1, ZI1);
    if (wid < 4) G1_TILE(wid + 16, ZR2, ZI2);
    __syncthreads();  // all T-plane reads done; LDS reused for Zcat

    Z_STORE(wid, ZR0, ZI0);
    Z_STORE(wid + 8, ZR1, ZI1);
    if (wid < 4) Z_STORE(wid + 16, ZR2, ZI2);
    __syncthreads();

    // GEMM2: out = EC @ Zcat.
    f32x4 acc[5] = {};
#pragma unroll
    for (int nt = 0; nt < 5; nt++) {
        int w = nt * 16 + ln;
#pragma unroll
        for (int kk = 0; kk < 4; kk++) {
            int oct = kk * 4 + kq;
            int ad = w * 128 + ((oct ^ (w & 7)) << 3);
            bf16x8 Bh = *(const bf16x8*)&lds[ad];
            bf16x8 Bl = *(const bf16x8*)&lds[10240 + ad];
            acc[nt] = __builtin_amdgcn_mfma_f32_16x16x32_bf16(ECh[kk], Bh, acc[nt], 0, 0, 0);
            acc[nt] = __builtin_amdgcn_mfma_f32_16x16x32_bf16(ECh[kk], Bl, acc[nt], 0, 0, 0);
            acc[nt] = __builtin_amdgcn_mfma_f32_16x16x32_bf16(ECl[kk], Bh, acc[nt], 0, 0, 0);
        }
    }
    float* op = out + (size_t)bo * 8320;
    const int h0 = wid * 16 + kq * 4;
#pragma unroll
    for (int nt = 0; nt < 5; nt++) {
        int w = nt * 16 + ln;
        if (w < 65) {
#pragma unroll
            for (int r = 0; r < 4; r++)
                op[(h0 + r) * 65 + w] = acc[nt][r];
        }
    }
}

extern "C" void kernel_launch(void* const* d_in, const int* in_sizes, int n_in,
                              void* d_out, int out_size, void* d_ws, size_t ws_size,
                              hipStream_t stream) {
    const float* x   = (const float*)d_in[0];
    const float* w1r = (const float*)d_in[1];
    const float* w1i = (const float*)d_in[2];
    const float* w2r = (const float*)d_in[3];
    const float* w2i = (const float*)d_in[4];
    float2* ws = (float2*)d_ws;

    // buf1 [0, 8388608) f2: Yimg (bf16 planes, 64 MB) then T (mix out).
    // buf2 [8388608, +4194304) f2: Xf.
    // Constant images after Xf (re-initialized every launch, never overwritten):
    //   e1 32 KiB, e2 64 KiB, ec 64 KiB, ew 30 KiB.
    ushort* yimg = (ushort*)ws;
    float2* ta   = ws;
    float2* xfa  = ws + 8388608;
    ushort* e1img = (ushort*)(ws + 12582912);
    ushort* e2img = (ushort*)(ws + 12587008);
    ushort* ecimg = (ushort*)(ws + 12595200);
    ushort* ewimg = (ushort*)(ws + 12603392);
    float* out = (float*)d_out;

    k_einit<<<160, 256, 0, stream>>>(e1img, e2img, ecimg, ewimg);
    k_f1<<<dim3(2048, 2), 256, 0, stream>>>(x, e1img, yimg);
    k_f2<<<256, 512, 0, stream>>>(yimg, e2img, xfa);
    k_mix<<<dim3(64, 4), 512, 0, stream>>>(xfa, w1r, w1i, w2r, w2i, ta);
    k_inv<<<2048, 512, 0, stream>>>(ta, ecimg, ewimg, out);
}